// Round 7
// baseline (31.253 us; speedup 1.0000x reference)
//
#include <hip/hip_runtime.h>

#define WINDOW 11
#define H 512
#define W 512
#define OH 502            // H - WINDOW + 1
#define OW 502
#define NCH 3
#define BATCH 8
#define RSTRIPE 16
#define NSTRIPES 32       // 32 stripes; stripe 31 computes rows 496..501 (masked to 502)
#define NGRP 5            // col groups: 4 x 118 outputs + 1 x 30
#define GRPW 118          // output cols per full group (64 lanes * 2 - 10 halo)
#define WAVES_PER_IMG (NSTRIPES * NGRP)                 // 160
#define NBLOCKS (BATCH * NCH * WAVES_PER_IMG / 4)       // 960

#define NPIX_PER_BATCH (3.0f * 502.0f * 502.0f)   // 756012

// ---- gfx9 DPP inclusive wave scan (64 lanes), VALU-pipe only ----
template <int CTRL, int RM>
__device__ __forceinline__ float scan_step(float x) {
    int s = __builtin_amdgcn_update_dpp(0, __builtin_bit_cast(int, x),
                                        CTRL, RM, 0xf, false);
    return x + __builtin_bit_cast(float, s);
}
__device__ __forceinline__ float wave_iscan(float x) {
    x = scan_step<0x111, 0xf>(x);   // row_shr:1
    x = scan_step<0x112, 0xf>(x);   // row_shr:2
    x = scan_step<0x114, 0xf>(x);   // row_shr:4
    x = scan_step<0x118, 0xf>(x);   // row_shr:8
    x = scan_step<0x142, 0xa>(x);   // row_bcast:15 -> rows 1,3
    x = scan_step<0x143, 0xc>(x);   // row_bcast:31 -> rows 2,3
    return x;
}

__device__ __forceinline__ float ssim_from(float sx, float sy, float s2, float sxy) {
    const float n = 121.0f;
    const float inv_n = 1.0f / 121.0f;
    const float inv_nm1 = 1.0f / 120.0f;
    const float c1 = 1e-4f;   // (0.01)^2
    const float c2 = 9e-4f;   // (0.03)^2
    float mx  = sx * inv_n;
    float my  = sy * inv_n;
    float mxy = mx * my;
    float m2  = mx * mx + my * my;
    float cov = (sxy - n * mxy) * inv_nm1;   // covariance
    float v2  = (s2  - n * m2)  * inv_nm1;   // vx + vy
    float num = (2.f * mxy + c1) * (2.f * cov + c2);
    float den = (m2 + c1) * (v2 + c2);
    return num * __builtin_amdgcn_rcpf(den);  // den >= 9e-8, rel err ~1e-7
}

__global__ __launch_bounds__(256) void ssim_main(const float* __restrict__ x,
                                                 const float* __restrict__ y,
                                                 float* __restrict__ partials) {
    __shared__ float red[4];

    const int t    = threadIdx.x;
    const int widx = t >> 6;
    const int lane = t & 63;
    const int w    = blockIdx.x * 4 + widx;    // global wave id

    const int grp = w % NGRP;
    const int rs  = (w / NGRP) % NSTRIPES;
    const int img = w / WAVES_PER_IMG;         // b*NCH + c

    const int i0 = rs * RSTRIPE;
    const int i1 = min(i0 + RSTRIPE, OH);      // 16 rows, stripe 31: 6 live rows
    const int cstart = grp * GRPW;             // first staged/output col
    const int outw   = min(GRPW, OW - cstart); // 118 or 30
    // clamped column pair: out-of-range lanes read real (unused) data
    const int c0 = min(cstart + 2 * lane, W - 2);
    const bool tapActive = (2 * lane < outw);

    const float* __restrict__ xi = x + (size_t)img * H * W;
    const float* __restrict__ yi = y + (size_t)img * H * W;
    const float* xc = xi + c0;                 // this lane's column base
    const float* yc = yi + c0;

    // --- init: vertical column sums for rows i0..i0+10, in registers ---
    float4 v0 = make_float4(0.f, 0.f, 0.f, 0.f);
    float4 v1 = make_float4(0.f, 0.f, 0.f, 0.f);
#pragma unroll
    for (int r = 0; r < WINDOW; ++r) {
        float2 a = *(const float2*)(xc + (size_t)(i0 + r) * W);
        float2 b = *(const float2*)(yc + (size_t)(i0 + r) * W);
        v0.x += a.x; v0.y += b.x; v0.z += a.x * a.x + b.x * b.x; v0.w += a.x * b.x;
        v1.x += a.y; v1.y += b.y; v1.z += a.y * a.y + b.y * b.y; v1.w += a.y * b.y;
    }

    // depth-4 pipeline register sets (static indices only)
    float2 xo[4], yo[4], xn[4], yn[4];

    // slide loads for row-iter j: old row j, new row j+11 (rows clamped; loads
    // whose results would be OOB feed only masked-out accumulations)
#define LD(j, u) do {                                                \
        int jc_ = min((j), H - 1);                                   \
        int rn_ = min((j) + WINDOW, H - 1);                          \
        xo[u] = *(const float2*)(xc + (size_t)jc_ * W);              \
        yo[u] = *(const float2*)(yc + (size_t)jc_ * W);              \
        xn[u] = *(const float2*)(xc + (size_t)rn_ * W);              \
        yn[u] = *(const float2*)(yc + (size_t)rn_ * W);              \
    } while (0)

#define SLIDE(u) do {                                                 \
        v0.x += xn[u].x - xo[u].x;                                    \
        v0.y += yn[u].x - yo[u].x;                                    \
        v0.z += xn[u].x * xn[u].x + yn[u].x * yn[u].x                 \
              - xo[u].x * xo[u].x - yo[u].x * yo[u].x;                \
        v0.w += xn[u].x * yn[u].x - xo[u].x * yo[u].x;                \
        v1.x += xn[u].y - xo[u].y;                                    \
        v1.y += yn[u].y - yo[u].y;                                    \
        v1.z += xn[u].y * xn[u].y + yn[u].y * yn[u].y                 \
              - xo[u].y * xo[u].y - yo[u].y * yo[u].y;                \
        v1.w += xn[u].y * yn[u].y - xo[u].y * yo[u].y;                \
    } while (0)

    float acc = 0.f;

    auto compute = [&](bool rowActive) {
        float Tx = v0.x + v1.x, Ty = v0.y + v1.y;
        float Tz = v0.z + v1.z, Tw = v0.w + v1.w;
        float Sx = wave_iscan(Tx), Sy = wave_iscan(Ty);
        float Sz = wave_iscan(Tz), Sw = wave_iscan(Tw);
        int src = lane + 5;
        float Ax = __shfl(Sx, src, 64), Ay = __shfl(Sy, src, 64);
        float Az = __shfl(Sz, src, 64), Aw = __shfl(Sw, src, 64);
        float Bx = __shfl(v1.x, src, 64), By = __shfl(v1.y, src, 64);
        float Bz = __shfl(v1.z, src, 64), Bw = __shfl(v1.w, src, 64);
        if (tapActive & rowActive) {
            acc += ssim_from(Ax - Bx - Sx + Tx, Ay - By - Sy + Ty,
                             Az - Bz - Sz + Tz, Aw - Bw - Sw + Tw);
            acc += ssim_from(Ax - Sx + v1.x, Ay - Sy + v1.y,
                             Az - Sz + v1.z, Aw - Sw + v1.w);
        }
    };

    // --- depth-4 software-pipelined main loop, constant 16-row trip ---
#pragma unroll
    for (int k = 0; k < 4; ++k) LD(i0 + k, k);

    for (int r = 0; r < RSTRIPE; r += 4) {
#pragma unroll
        for (int u = 0; u < 4; ++u) {
            const int i = i0 + r + u;
            compute(i < i1);              // wave-uniform row mask
            SLIDE(u);                     // -> window for row i+1
            LD(i + 4, u);                 // prefetch 4 row-iters ahead
        }
    }

    // --- per-wave then per-block reduction (fixed order, deterministic) ---
    for (int off = 32; off > 0; off >>= 1)
        acc += __shfl_down(acc, off, 64);
    if (lane == 0) red[widx] = acc;
    __syncthreads();
    if (t == 0)
        partials[blockIdx.x] = (red[0] + red[1]) + (red[2] + red[3]);
}

__global__ __launch_bounds__(256) void ssim_reduce(const float* __restrict__ partials,
                                                   float* __restrict__ out) {
    const int b = blockIdx.x;          // one block per batch element
    const int t = threadIdx.x;
    const int per = NBLOCKS / BATCH;   // 120 contiguous block-partials per batch
    float s = 0.f;
    for (int k = t; k < per; k += 256)
        s += partials[b * per + k];
    for (int off = 32; off > 0; off >>= 1)
        s += __shfl_down(s, off, 64);
    __shared__ float red[4];
    int wid = t >> 6, lane = t & 63;
    if (lane == 0) red[wid] = s;
    __syncthreads();
    if (t == 0) {
        float tot = (red[0] + red[1]) + (red[2] + red[3]);
        out[b] = (1.0f - tot / NPIX_PER_BATCH) * 0.5f;
    }
}

extern "C" void kernel_launch(void* const* d_in, const int* in_sizes, int n_in,
                              void* d_out, int out_size, void* d_ws, size_t ws_size,
                              hipStream_t stream) {
    const float* x = (const float*)d_in[0];
    const float* y = (const float*)d_in[1];
    float* out      = (float*)d_out;
    float* partials = (float*)d_ws;   // 960 floats, fully overwritten each call

    ssim_main<<<NBLOCKS, 256, 0, stream>>>(x, y, partials);
    ssim_reduce<<<BATCH, 256, 0, stream>>>(partials, out);
}